// Round 1
// 1000.943 us; speedup vs baseline: 1.0117x; 1.0117x over previous
//
#include <hip/hip_runtime.h>
#include <math.h>

// GAT: 3 hidden GATConv layers (H=4, D=64, HID=256) + LN + leaky + residual,
// then output GATConv (H=1, C=40). N=100000 nodes, E=1600000 edges.
//
// Round 10: (1) aggregate_hidden: half-wave edge pairing. Each 32-lane half
// owns one edge per step (ushort8 = 16B/lane, 8 channels/lane); halves the
// feat/el load instruction count and the redundant per-head weight compute
// (exp/leaky) that was keeping VALUBusy at 60%. One xor-32 shuffle combine
// per node merges the halves. Traffic and coalescing unchanged (1KB per
// load instr covering 2 edge rows). (2) scores_out folded into the
// gemm_out_mfma epilogue (fp32-accumulator head dots, 16-lane reduce).

#define NEG_SLOPE 0.2f

typedef __attribute__((ext_vector_type(8))) short bf16x8;
typedef __attribute__((ext_vector_type(4))) float floatx4;
typedef __attribute__((ext_vector_type(8))) unsigned short ushort8v;

__device__ __forceinline__ float leaky(float x) { return x >= 0.f ? x : NEG_SLOPE * x; }

__device__ __forceinline__ unsigned short f2bf(float f) {
    unsigned u = __builtin_bit_cast(unsigned, f);
    u += 0x7fffu + ((u >> 16) & 1u);  // RNE
    return (unsigned short)(u >> 16);
}
__device__ __forceinline__ float bf2f(unsigned short h) {
    unsigned u = ((unsigned)h) << 16;
    return __builtin_bit_cast(float, u);
}

// ---------------- CSR build ----------------
__global__ void zero_i32(int* __restrict__ p, int n) {
    int i = blockIdx.x * blockDim.x + threadIdx.x;
    if (i < n) p[i] = 0;
}

__global__ void hist_kernel(const int* __restrict__ dst, int* __restrict__ counts, int E) {
    int e = blockIdx.x * blockDim.x + threadIdx.x;
    if (e < E) atomicAdd(&counts[dst[e]], 1);
}

__global__ void alloc_kernel(const int* __restrict__ counts, int* __restrict__ start,
                             int* __restrict__ cursor, int* __restrict__ total, int N) {
    int n = blockIdx.x * blockDim.x + threadIdx.x;
    if (n < N) {
        int c = counts[n];
        int s = atomicAdd(total, c);
        start[n] = s;
        cursor[n] = s;
    }
}

__global__ void scatter_kernel(const int* __restrict__ src, const int* __restrict__ dst,
                               int* __restrict__ cursor, int* __restrict__ col, int E) {
    int e = blockIdx.x * blockDim.x + threadIdx.x;
    if (e < E) {
        int p = atomicAdd(&cursor[dst[e]], 1);
        col[p] = src[e];
    }
}

// ---------------- fp32 -> bf16 bulk convert ----------------
__global__ void convert_bf(const float* __restrict__ src, unsigned short* __restrict__ dst,
                           int n4) {
    int i = blockIdx.x * blockDim.x + threadIdx.x;
    if (i < n4) {
        float4 v = *(const float4*)(src + (size_t)i * 4);
        ushort4 s;
        s.x = f2bf(v.x); s.y = f2bf(v.y); s.z = f2bf(v.z); s.w = f2bf(v.w);
        *(ushort4*)(dst + (size_t)i * 4) = s;
    }
}

// ---------------- weight pre-transpose: Wt[l][n][k] = bf16(W[l][k][n]) ----------------
__global__ void transpose_w(const float* __restrict__ W, unsigned short* __restrict__ Wt) {
    int idx = blockIdx.x * 256 + threadIdx.x;
    int l = idx >> 16, r = idx & 65535;
    int k = r >> 8, n = r & 255;
    Wt[l * 65536 + n * 256 + k] = f2bf(W[l * 65536 + k * 256 + n]);
}

__global__ void transpose_wo(const float* __restrict__ W, unsigned short* __restrict__ Wt) {
    int idx = blockIdx.x * 256 + threadIdx.x;
    int n = idx >> 8, k = idx & 255;
    Wt[n * 256 + k] = (n < 40) ? f2bf(W[k * 40 + n]) : (unsigned short)0;
}

// ---------------- bf16 MFMA GEMM + fused attention scores ----------------
// Cb[M,256] = bf16(A @ W); el/er[M,4] = head dots from fp32 accumulators.
#define LDSK 40
__global__ __launch_bounds__(256, 2) void gemm_bf16_fused(
    const unsigned short* __restrict__ A, const unsigned short* __restrict__ Wt,
    const float* __restrict__ al, const float* __restrict__ ar,
    unsigned short* __restrict__ Cb, float* __restrict__ el, float* __restrict__ er, int M) {
    __shared__ unsigned short As[128 * LDSK];
    __shared__ unsigned short Bs[128 * LDSK];
    const int tid = threadIdx.x;
    const int bx = blockIdx.x & 1;
    const int by = blockIdx.x >> 1;
    const int row0 = by * 128, col0 = bx * 128;
    const int lane = tid & 63, wid = tid >> 6;
    const int wm = (wid & 1) * 64, wn = (wid >> 1) * 64;

    const int rA = tid >> 2, k8 = (tid & 3) * 8;
    auto loadA = [&](int kb, int rr) -> bf16x8 {
        int gr = row0 + rr;
        bf16x8 v = {};
        if (gr < M) v = *(const bf16x8*)(A + (size_t)gr * 256 + kb + k8);
        return v;
    };
    auto loadB = [&](int kb, int rr) -> bf16x8 {
        return *(const bf16x8*)(Wt + (size_t)(col0 + rr) * 256 + kb + k8);
    };

    floatx4 acc[4][4] = {};
    bf16x8 pa0 = loadA(0, rA), pa1 = loadA(0, rA + 64);
    bf16x8 pb0 = loadB(0, rA), pb1 = loadB(0, rA + 64);

    const int q = lane >> 4, m = lane & 15;
    for (int kb = 0; kb < 256; kb += 32) {
        *(bf16x8*)&As[rA * LDSK + k8] = pa0;
        *(bf16x8*)&As[(rA + 64) * LDSK + k8] = pa1;
        *(bf16x8*)&Bs[rA * LDSK + k8] = pb0;
        *(bf16x8*)&Bs[(rA + 64) * LDSK + k8] = pb1;
        __syncthreads();
        int nkb = kb + 32;
        if (nkb < 256) {  // prefetch next chunk; overlaps with ds_read+MFMA below
            pa0 = loadA(nkb, rA); pa1 = loadA(nkb, rA + 64);
            pb0 = loadB(nkb, rA); pb1 = loadB(nkb, rA + 64);
        }
        bf16x8 af[4], bfr[4];
#pragma unroll
        for (int i = 0; i < 4; ++i) {
            af[i] = *(const bf16x8*)&As[(wm + i * 16 + m) * LDSK + q * 8];
            bfr[i] = *(const bf16x8*)&Bs[(wn + i * 16 + m) * LDSK + q * 8];
        }
#pragma unroll
        for (int i = 0; i < 4; ++i)
#pragma unroll
            for (int j = 0; j < 4; ++j)
                acc[i][j] = __builtin_amdgcn_mfma_f32_16x16x32_bf16(af[i], bfr[j], acc[i][j], 0, 0, 0);
        __syncthreads();
    }

    // epilogue: C store (layout col=lane&15, row=q*4+reg) + fused head dots
    const int c = lane & 15;
#pragma unroll
    for (int i = 0; i < 4; ++i)
#pragma unroll
        for (int j = 0; j < 4; ++j)
#pragma unroll
            for (int r = 0; r < 4; ++r) {
                int grow = row0 + wm + i * 16 + q * 4 + r;
                int gcol = col0 + wn + j * 16 + c;
                if (grow < M) Cb[(size_t)grow * 256 + gcol] = f2bf(acc[i][j][r]);
            }

    const int head = bx * 2 + (wn >> 6);          // this wave's head
    const float* alh = al + head * 64;
    const float* arh = ar + head * 64;
    float a0 = alh[c], a1 = alh[16 + c], a2 = alh[32 + c], a3 = alh[48 + c];
    float r0 = arh[c], r1 = arh[16 + c], r2 = arh[32 + c], r3 = arh[48 + c];
#pragma unroll
    for (int i = 0; i < 4; ++i)
#pragma unroll
        for (int r = 0; r < 4; ++r) {
            float pel = acc[i][0][r] * a0 + acc[i][1][r] * a1 + acc[i][2][r] * a2 + acc[i][3][r] * a3;
            float per = acc[i][0][r] * r0 + acc[i][1][r] * r1 + acc[i][2][r] * r2 + acc[i][3][r] * r3;
#pragma unroll
            for (int off = 8; off >= 1; off >>= 1) {
                pel += __shfl_xor(pel, off);
                per += __shfl_xor(per, off);
            }
            if (c == 0) {
                int grow = row0 + wm + i * 16 + q * 4 + r;
                if (grow < M) {
                    el[(size_t)grow * 4 + head] = pel;
                    er[(size_t)grow * 4 + head] = per;
                }
            }
        }
}

// ---------------- output MFMA GEMM: feat_o[N,40] bf16 = h_bf[N,256] @ W_o ----------------
// + fused output attention scores elo/ero[N] (replaces scores_out pass).
#define BSTRIDE 264
__global__ __launch_bounds__(256) void gemm_out_mfma(const unsigned short* __restrict__ h,
                                                     const unsigned short* __restrict__ Wt,
                                                     const float* __restrict__ alo,
                                                     const float* __restrict__ aro,
                                                     unsigned short* __restrict__ feat_o,
                                                     float* __restrict__ elo,
                                                     float* __restrict__ ero, int N) {
    __shared__ unsigned short As[128 * LDSK];
    __shared__ unsigned short Bs[48 * BSTRIDE];
    const int tid = threadIdx.x;
    const int row0 = blockIdx.x * 128;
    const int lane = tid & 63, wid = tid >> 6;

#pragma unroll
    for (int i = 0; i < 6; ++i) {
        int f = tid + 256 * i;
        int n = f >> 5, kk = (f & 31) * 8;
        *(bf16x8*)&Bs[n * BSTRIDE + kk] = *(const bf16x8*)(Wt + n * 256 + kk);
    }
    __syncthreads();

    floatx4 acc[2][3] = {};
    for (int kb = 0; kb < 256; kb += 32) {
#pragma unroll
        for (int i = 0; i < 2; ++i) {
            int idx = tid + 256 * i;
            int r = idx >> 2, k8 = (idx & 3) * 8;
            int gr = row0 + r;
            bf16x8 v = {};
            if (gr < N) v = *(const bf16x8*)(h + (size_t)gr * 256 + kb + k8);
            *(bf16x8*)&As[r * LDSK + k8] = v;
        }
        __syncthreads();
        const int q = lane >> 4, m = lane & 15;
        bf16x8 af[2], bfr[3];
#pragma unroll
        for (int i = 0; i < 2; ++i)
            af[i] = *(const bf16x8*)&As[(wid * 32 + i * 16 + m) * LDSK + q * 8];
#pragma unroll
        for (int j = 0; j < 3; ++j)
            bfr[j] = *(const bf16x8*)&Bs[(j * 16 + m) * BSTRIDE + kb + q * 8];
#pragma unroll
        for (int i = 0; i < 2; ++i)
#pragma unroll
            for (int j = 0; j < 3; ++j)
                acc[i][j] = __builtin_amdgcn_mfma_f32_16x16x32_bf16(af[i], bfr[j], acc[i][j], 0, 0, 0);
        __syncthreads();
    }

    const int q = lane >> 4, c = lane & 15;
#pragma unroll
    for (int i = 0; i < 2; ++i)
#pragma unroll
        for (int j = 0; j < 3; ++j)
#pragma unroll
            for (int r = 0; r < 4; ++r) {
                int grow = row0 + wid * 32 + i * 16 + q * 4 + r;
                int gcol = j * 16 + c;
                if (grow < N && gcol < 40) feat_o[(size_t)grow * 40 + gcol] = f2bf(acc[i][j][r]);
            }

    // fused output scores: dot over 40 cols from fp32 accumulators
    float aj[3], rj[3];
#pragma unroll
    for (int j = 0; j < 3; ++j) {
        int gcol = j * 16 + c;
        aj[j] = gcol < 40 ? alo[gcol] : 0.f;
        rj[j] = gcol < 40 ? aro[gcol] : 0.f;
    }
#pragma unroll
    for (int i = 0; i < 2; ++i)
#pragma unroll
        for (int r = 0; r < 4; ++r) {
            float pl = acc[i][0][r] * aj[0] + acc[i][1][r] * aj[1] + acc[i][2][r] * aj[2];
            float pr = acc[i][0][r] * rj[0] + acc[i][1][r] * rj[1] + acc[i][2][r] * rj[2];
#pragma unroll
            for (int off = 8; off >= 1; off >>= 1) {
                pl += __shfl_xor(pl, off);
                pr += __shfl_xor(pr, off);
            }
            if (c == 0) {
                int grow = row0 + wid * 32 + i * 16 + q * 4 + r;
                if (grow < N) {
                    elo[grow] = pl;
                    ero[grow] = pr;
                }
            }
        }
}

// ---------------- hidden-layer aggregation: half-wave edge pairing ----------------
// Lanes 0-31 process even-indexed edges, lanes 32-63 odd-indexed. Each lane
// owns 8 channels (ch = (lane&31)*8, ushort8 loads). One xor-32 combine at
// the end merges halves. 2 edge rows fetched per wave load instruction.
__global__ __launch_bounds__(256) void aggregate_hidden(
    const unsigned short* __restrict__ feat, const float* __restrict__ el,
    const float* __restrict__ er, const int* __restrict__ start, const int* __restrict__ endp,
    const int* __restrict__ col, const float* __restrict__ bias, const float* __restrict__ lng,
    const float* __restrict__ lnb, const unsigned short* __restrict__ h_in,
    unsigned short* __restrict__ h_out, int N) {
    int node = blockIdx.x * 4 + (threadIdx.x >> 6);
    int lane = threadIdx.x & 63;
    if (node >= N) return;
    int begin = __builtin_amdgcn_readfirstlane(start[node]);
    int end = __builtin_amdgcn_readfirstlane(endp[node]);
    const int hl = lane & 31;     // lane within half
    const int half = lane >> 5;   // which edge of the pair
    const int head = hl >> 3;     // 8 channels/lane -> 8 lanes/head
    const float erh = er[(size_t)node * 4 + head];
    const int ch = hl * 8;
    const unsigned short* fbase = feat + ch;

    float acc[8] = {};
    float ssum = 0.f;
    int e = begin;
    for (; e + 7 < end; e += 8) {
        int c0 = col[e], c1 = col[e + 1], c2 = col[e + 2], c3 = col[e + 3];
        int c4 = col[e + 4], c5 = col[e + 5], c6 = col[e + 6], c7 = col[e + 7];
        int sA = half ? c1 : c0;
        int sB = half ? c3 : c2;
        int sC = half ? c5 : c4;
        int sD = half ? c7 : c6;
        float eA = el[(size_t)sA * 4 + head];
        float eB = el[(size_t)sB * 4 + head];
        float eC = el[(size_t)sC * 4 + head];
        float eD = el[(size_t)sD * 4 + head];
        ushort8v uA = *(const ushort8v*)(fbase + (size_t)sA * 256);
        ushort8v uB = *(const ushort8v*)(fbase + (size_t)sB * 256);
        ushort8v uC = *(const ushort8v*)(fbase + (size_t)sC * 256);
        ushort8v uD = *(const ushort8v*)(fbase + (size_t)sD * 256);
        float wA = __expf(leaky(eA + erh));
        float wB = __expf(leaky(eB + erh));
        float wC = __expf(leaky(eC + erh));
        float wD = __expf(leaky(eD + erh));
        ssum += wA + wB + wC + wD;
#pragma unroll
        for (int i = 0; i < 8; ++i) {
            acc[i] = fmaf(wA, bf2f(uA[i]), acc[i]);
            acc[i] = fmaf(wB, bf2f(uB[i]), acc[i]);
            acc[i] = fmaf(wC, bf2f(uC[i]), acc[i]);
            acc[i] = fmaf(wD, bf2f(uD[i]), acc[i]);
        }
    }
    for (; e + 1 < end; e += 2) {
        int c0 = col[e], c1 = col[e + 1];
        int s = half ? c1 : c0;
        float ee = el[(size_t)s * 4 + head];
        ushort8v u = *(const ushort8v*)(fbase + (size_t)s * 256);
        float w = __expf(leaky(ee + erh));
        ssum += w;
#pragma unroll
        for (int i = 0; i < 8; ++i) acc[i] = fmaf(w, bf2f(u[i]), acc[i]);
    }
    if (e < end) {  // odd tail: half B contributes zero weight
        int s = col[e];
        float ee = el[(size_t)s * 4 + head];
        ushort8v u = *(const ushort8v*)(fbase + (size_t)s * 256);
        float w = half ? 0.f : __expf(leaky(ee + erh));
        ssum += w;
#pragma unroll
        for (int i = 0; i < 8; ++i) acc[i] = fmaf(w, bf2f(u[i]), acc[i]);
    }

    // merge halves (each half holds all 256 channels for its edge subset)
    ssum += __shfl_xor(ssum, 32);
#pragma unroll
    for (int i = 0; i < 8; ++i) acc[i] += __shfl_xor(acc[i], 32);
    float inv = ssum > 0.f ? 1.f / ssum : 0.f;

    float4 b0 = *(const float4*)(bias + ch);
    float4 b1 = *(const float4*)(bias + ch + 4);
    float bb[8] = {b0.x, b0.y, b0.z, b0.w, b1.x, b1.y, b1.z, b1.w};
    float x[8];
    float lsum = 0.f, lsq = 0.f;
#pragma unroll
    for (int i = 0; i < 8; ++i) {
        float v = acc[i] * inv + bb[i];
        v = v > 0.f ? v : expm1f(v);
        x[i] = v;
        lsum += v;
        lsq += v * v;
    }
#pragma unroll
    for (int off = 16; off >= 1; off >>= 1) {  // within-half butterfly: 32 lanes x 8 ch = 256
        lsum += __shfl_xor(lsum, off);
        lsq += __shfl_xor(lsq, off);
    }
    float mu = lsum * (1.f / 256.f);
    float var = lsq * (1.f / 256.f) - mu * mu;
    float rstd = rsqrtf(var + 1e-5f);
    if (half) return;  // lanes 0-31 hold the full row; they do the write
    float4 g0 = *(const float4*)(lng + ch);
    float4 g1 = *(const float4*)(lng + ch + 4);
    float4 p0 = *(const float4*)(lnb + ch);
    float4 p1 = *(const float4*)(lnb + ch + 4);
    float gg[8] = {g0.x, g0.y, g0.z, g0.w, g1.x, g1.y, g1.z, g1.w};
    float pp[8] = {p0.x, p0.y, p0.z, p0.w, p1.x, p1.y, p1.z, p1.w};
    ushort8v hi8 = *(const ushort8v*)(h_in + (size_t)node * 256 + ch);
    ushort8v o;
#pragma unroll
    for (int i = 0; i < 8; ++i) {
        float y = (x[i] - mu) * rstd * gg[i] + pp[i];
        y = (y >= 0.f ? y : 0.2f * y) + bf2f(hi8[i]);
        o[i] = f2bf(y);
    }
    *(ushort8v*)(h_out + (size_t)node * 256 + ch) = o;
}

// ---------------- output aggregation: logits[N,40], single pass ----------------
__global__ __launch_bounds__(256) void aggregate_out(const unsigned short* __restrict__ feat_o,
                                                     const float* __restrict__ elo,
                                                     const float* __restrict__ ero,
                                                     const int* __restrict__ start,
                                                     const int* __restrict__ endp,
                                                     const int* __restrict__ col,
                                                     const float* __restrict__ bias_o,
                                                     float* __restrict__ out, int N) {
    int node = blockIdx.x * 4 + (threadIdx.x >> 6);
    int lane = threadIdx.x & 63;
    if (node >= N) return;
    int begin = __builtin_amdgcn_readfirstlane(start[node]);
    int end = __builtin_amdgcn_readfirstlane(endp[node]);
    float ern = ero[node];
    int cc = lane < 40 ? lane : 0;
    float acc = 0.f, ssum = 0.f;
    int e = begin;
    for (; e + 7 < end; e += 8) {
        int sA = col[e], sB = col[e + 1], sC = col[e + 2], sD = col[e + 3];
        int sE = col[e + 4], sF = col[e + 5], sG = col[e + 6], sH = col[e + 7];
        float eA = elo[sA], eB = elo[sB], eC = elo[sC], eD = elo[sD];
        float eE = elo[sE], eF = elo[sF], eG = elo[sG], eH = elo[sH];
        unsigned short fA = feat_o[(size_t)sA * 40 + cc];
        unsigned short fB = feat_o[(size_t)sB * 40 + cc];
        unsigned short fC = feat_o[(size_t)sC * 40 + cc];
        unsigned short fD = feat_o[(size_t)sD * 40 + cc];
        unsigned short fE = feat_o[(size_t)sE * 40 + cc];
        unsigned short fF = feat_o[(size_t)sF * 40 + cc];
        unsigned short fG = feat_o[(size_t)sG * 40 + cc];
        unsigned short fH = feat_o[(size_t)sH * 40 + cc];
        float wA = __expf(leaky(eA + ern));
        float wB = __expf(leaky(eB + ern));
        float wC = __expf(leaky(eC + ern));
        float wD = __expf(leaky(eD + ern));
        float wE = __expf(leaky(eE + ern));
        float wF = __expf(leaky(eF + ern));
        float wG = __expf(leaky(eG + ern));
        float wH = __expf(leaky(eH + ern));
        ssum += wA + wB + wC + wD + wE + wF + wG + wH;
        acc = fmaf(wA, bf2f(fA), acc);
        acc = fmaf(wB, bf2f(fB), acc);
        acc = fmaf(wC, bf2f(fC), acc);
        acc = fmaf(wD, bf2f(fD), acc);
        acc = fmaf(wE, bf2f(fE), acc);
        acc = fmaf(wF, bf2f(fF), acc);
        acc = fmaf(wG, bf2f(fG), acc);
        acc = fmaf(wH, bf2f(fH), acc);
    }
    for (; e < end; ++e) {
        int sA = col[e];
        float wA = __expf(leaky(elo[sA] + ern));
        ssum += wA;
        acc = fmaf(wA, bf2f(feat_o[(size_t)sA * 40 + cc]), acc);
    }
    float inv = ssum > 0.f ? 1.f / ssum : 0.f;
    if (lane < 40) out[(size_t)node * 40 + lane] = acc * inv + bias_o[lane];
}

// ---------------- launcher ----------------
extern "C" void kernel_launch(void* const* d_in, const int* in_sizes, int n_in,
                              void* d_out, int out_size, void* d_ws, size_t ws_size,
                              hipStream_t stream) {
    const float* x = (const float*)d_in[0];
    const float* W_h = (const float*)d_in[1];
    const float* al_h = (const float*)d_in[2];
    const float* ar_h = (const float*)d_in[3];
    const float* bias_h = (const float*)d_in[4];
    const float* ln_g = (const float*)d_in[5];
    const float* ln_b = (const float*)d_in[6];
    const float* W_o = (const float*)d_in[7];
    const float* al_o = (const float*)d_in[8];
    const float* ar_o = (const float*)d_in[9];
    const float* bias_o = (const float*)d_in[10];
    const int* esrc = (const int*)d_in[11];
    const int* edst = (const int*)d_in[12];
    const int N = in_sizes[0] / 256;
    const int E = in_sizes[11];
    float* out = (float*)d_out;

    char* ws = (char*)d_ws;
    size_t off = 0;
    auto walloc = [&](size_t bytes) -> void* {
        void* p = ws + off;
        off += (bytes + 255) & ~(size_t)255;
        return p;
    };
    unsigned short* x_bf = (unsigned short*)walloc((size_t)N * 256 * 2);
    unsigned short* h_bf = (unsigned short*)walloc((size_t)N * 256 * 2);
    unsigned short* feat_bf = (unsigned short*)walloc((size_t)N * 256 * 2);
    unsigned short* Wt = (unsigned short*)walloc((size_t)3 * 65536 * 2);
    unsigned short* Wt_o = (unsigned short*)walloc((size_t)48 * 256 * 2);
    float* el = (float*)walloc((size_t)N * 4 * 4);
    float* er = (float*)walloc((size_t)N * 4 * 4);
    int* counts = (int*)walloc(((size_t)N + 1) * 4);
    int* start = (int*)walloc((size_t)N * 4);
    int* endp = (int*)walloc((size_t)N * 4);
    int* col = (int*)walloc((size_t)E * 4);
    if (off > ws_size) return;

    const int TB = 256;
    convert_bf<<<(N * 64 + TB - 1) / TB, TB, 0, stream>>>(x, x_bf, N * 64);
    transpose_w<<<3 * 65536 / TB, TB, 0, stream>>>(W_h, Wt);
    transpose_wo<<<48, TB, 0, stream>>>(W_o, Wt_o);
    zero_i32<<<(N + 1 + TB - 1) / TB, TB, 0, stream>>>(counts, N + 1);
    hist_kernel<<<(E + TB - 1) / TB, TB, 0, stream>>>(edst, counts, E);
    alloc_kernel<<<(N + TB - 1) / TB, TB, 0, stream>>>(counts, start, endp, counts + N, N);
    scatter_kernel<<<(E + TB - 1) / TB, TB, 0, stream>>>(esrc, edst, endp, col, E);

    const int nb4 = (N + 3) / 4;
    const int gemm_grid = ((N + 127) / 128) * 2;
    for (int l = 0; l < 3; ++l) {
        const unsigned short* hin = (l == 0) ? x_bf : h_bf;
        gemm_bf16_fused<<<gemm_grid, 256, 0, stream>>>(hin, Wt + (size_t)l * 65536,
                                                       al_h + l * 256, ar_h + l * 256,
                                                       feat_bf, el, er, N);
        aggregate_hidden<<<nb4, 256, 0, stream>>>(feat_bf, el, er, start, endp, col,
                                                  bias_h + l * 256, ln_g + l * 256,
                                                  ln_b + l * 256, hin, h_bf, N);
    }
    unsigned short* feat_o = feat_bf;
    float* elo = el;
    float* ero = er;
    gemm_out_mfma<<<(N + 127) / 128, 256, 0, stream>>>(h_bf, Wt_o, al_o, ar_o, feat_o, elo, ero, N);
    aggregate_out<<<nb4, 256, 0, stream>>>(feat_o, elo, ero, start, endp, col, bias_o, out, N);
}

// Round 2
// 986.875 us; speedup vs baseline: 1.0261x; 1.0143x over previous
//
#include <hip/hip_runtime.h>
#include <math.h>

// GAT: 3 hidden GATConv layers (H=4, D=64, HID=256) + LN + leaky + residual,
// then output GATConv (H=1, C=40). N=100000 nodes, E=1600000 edges.
//
// Round 11: (1) aggregate_hidden reverted to R9 64-lane form (R10 half-wave
// was neutral-to-worse: gather-path-bound, not VALU-bound). (2) gemm_bf16_fused
// rewritten m97-style: 128x256 tile (full N), 512 thr / 8 waves (64x64 each),
// global_load_lds width-16 staging (no staging VGPRs -> no spills), double-
// buffered LDS 2-phase pipeline. Fused el/er epilogue kept (head = wid&3).
// (3) scores_out stays fused into gemm_out_mfma epilogue.

#define NEG_SLOPE 0.2f

typedef __attribute__((ext_vector_type(8))) short bf16x8;
typedef __attribute__((ext_vector_type(4))) float floatx4;

__device__ __forceinline__ float leaky(float x) { return x >= 0.f ? x : NEG_SLOPE * x; }

__device__ __forceinline__ unsigned short f2bf(float f) {
    unsigned u = __builtin_bit_cast(unsigned, f);
    u += 0x7fffu + ((u >> 16) & 1u);  // RNE
    return (unsigned short)(u >> 16);
}
__device__ __forceinline__ float bf2f(unsigned short h) {
    unsigned u = ((unsigned)h) << 16;
    return __builtin_bit_cast(float, u);
}

// async global->LDS, 16B per lane (global_load_lds_dwordx4)
typedef const __attribute__((address_space(1))) unsigned int* as1_u32p;
typedef __attribute__((address_space(3))) unsigned int* as3_u32p;
__device__ __forceinline__ void gl_lds16(const void* g, void* l) {
    __builtin_amdgcn_global_load_lds((as1_u32p)g, (as3_u32p)l, 16, 0, 0);
}

// ---------------- CSR build ----------------
__global__ void zero_i32(int* __restrict__ p, int n) {
    int i = blockIdx.x * blockDim.x + threadIdx.x;
    if (i < n) p[i] = 0;
}

__global__ void hist_kernel(const int* __restrict__ dst, int* __restrict__ counts, int E) {
    int e = blockIdx.x * blockDim.x + threadIdx.x;
    if (e < E) atomicAdd(&counts[dst[e]], 1);
}

__global__ void alloc_kernel(const int* __restrict__ counts, int* __restrict__ start,
                             int* __restrict__ cursor, int* __restrict__ total, int N) {
    int n = blockIdx.x * blockDim.x + threadIdx.x;
    if (n < N) {
        int c = counts[n];
        int s = atomicAdd(total, c);
        start[n] = s;
        cursor[n] = s;
    }
}

__global__ void scatter_kernel(const int* __restrict__ src, const int* __restrict__ dst,
                               int* __restrict__ cursor, int* __restrict__ col, int E) {
    int e = blockIdx.x * blockDim.x + threadIdx.x;
    if (e < E) {
        int p = atomicAdd(&cursor[dst[e]], 1);
        col[p] = src[e];
    }
}

// ---------------- fp32 -> bf16 bulk convert ----------------
__global__ void convert_bf(const float* __restrict__ src, unsigned short* __restrict__ dst,
                           int n4) {
    int i = blockIdx.x * blockDim.x + threadIdx.x;
    if (i < n4) {
        float4 v = *(const float4*)(src + (size_t)i * 4);
        ushort4 s;
        s.x = f2bf(v.x); s.y = f2bf(v.y); s.z = f2bf(v.z); s.w = f2bf(v.w);
        *(ushort4*)(dst + (size_t)i * 4) = s;
    }
}

// ---------------- weight pre-transpose: Wt[l][n][k] = bf16(W[l][k][n]) ----------------
__global__ void transpose_w(const float* __restrict__ W, unsigned short* __restrict__ Wt) {
    int idx = blockIdx.x * 256 + threadIdx.x;
    int l = idx >> 16, r = idx & 65535;
    int k = r >> 8, n = r & 255;
    Wt[l * 65536 + n * 256 + k] = f2bf(W[l * 65536 + k * 256 + n]);
}

__global__ void transpose_wo(const float* __restrict__ W, unsigned short* __restrict__ Wt) {
    int idx = blockIdx.x * 256 + threadIdx.x;
    int n = idx >> 8, k = idx & 255;
    Wt[n * 256 + k] = (n < 40) ? f2bf(W[k * 40 + n]) : (unsigned short)0;
}

// ---------------- bf16 MFMA GEMM + fused attention scores (m97-style) ----------------
// Block: 128 rows x 256 cols, 512 threads (8 waves, 64x64 each).
// Staging: global_load_lds dwordx4, double-buffered [128][32] A / [256][32] B.
// Cb[M,256] = bf16(A @ W); el/er[M,4] = head dots from fp32 accumulators.
__global__ __launch_bounds__(512, 4) void gemm_bf16_fused(
    const unsigned short* __restrict__ A, const unsigned short* __restrict__ Wt,
    const float* __restrict__ al, const float* __restrict__ ar,
    unsigned short* __restrict__ Cb, float* __restrict__ el, float* __restrict__ er, int M) {
    __shared__ unsigned short As[2][128 * 32];
    __shared__ unsigned short Bs[2][256 * 32];
    const int tid = threadIdx.x;
    const int row0 = blockIdx.x * 128;
    const int lane = tid & 63, wid = tid >> 6;
    const int wm = (wid >> 2) * 64;   // 0 or 64
    const int wn = (wid & 3) * 64;    // 0,64,128,192

    // staging geometry: per wave-inst 64 lanes x 16B = 1KB = 16 rows of [32] bf16
    const int arow = wid * 16 + (lane >> 2);        // A: wave stages rows wid*16..+16
    const int brow0 = wid * 32 + (lane >> 2);       // B: wave stages rows wid*32..+32
    const int kx = (lane & 3) * 8;                  // 8 bf16 = 16B within row
    const int agr = (row0 + arow < M) ? (row0 + arow) : (M - 1);  // clamp OOB rows

    auto stage = [&](int buf, int kb) {
        gl_lds16(A + (size_t)agr * 256 + kb + kx, &As[buf][arow * 32 + kx]);
        gl_lds16(Wt + (size_t)brow0 * 256 + kb + kx, &Bs[buf][brow0 * 32 + kx]);
        gl_lds16(Wt + (size_t)(brow0 + 16) * 256 + kb + kx, &Bs[buf][(brow0 + 16) * 32 + kx]);
    };

    floatx4 acc[4][4] = {};
    const int q = lane >> 4, m = lane & 15;

    stage(0, 0);
    __syncthreads();
    int cur = 0;
    for (int kb = 0; kb < 256; kb += 32) {
        int nkb = kb + 32;
        if (nkb < 256) stage(cur ^ 1, nkb);
        bf16x8 af[4], bfr[4];
#pragma unroll
        for (int i = 0; i < 4; ++i) {
            af[i] = *(const bf16x8*)&As[cur][(wm + i * 16 + m) * 32 + q * 8];
            bfr[i] = *(const bf16x8*)&Bs[cur][(wn + i * 16 + m) * 32 + q * 8];
        }
#pragma unroll
        for (int i = 0; i < 4; ++i)
#pragma unroll
            for (int j = 0; j < 4; ++j)
                acc[i][j] = __builtin_amdgcn_mfma_f32_16x16x32_bf16(af[i], bfr[j], acc[i][j], 0, 0, 0);
        __syncthreads();   // drains vmcnt: next buffer ready for all waves
        cur ^= 1;
    }

    // epilogue: C store (layout col=lane&15, row=q*4+reg) + fused head dots
    const int c = lane & 15;
#pragma unroll
    for (int i = 0; i < 4; ++i)
#pragma unroll
        for (int j = 0; j < 4; ++j)
#pragma unroll
            for (int r = 0; r < 4; ++r) {
                int grow = row0 + wm + i * 16 + q * 4 + r;
                int gcol = wn + j * 16 + c;
                if (grow < M) Cb[(size_t)grow * 256 + gcol] = f2bf(acc[i][j][r]);
            }

    const int head = wid & 3;                     // this wave's head (wn/64)
    const float* alh = al + head * 64;
    const float* arh = ar + head * 64;
    float a0 = alh[c], a1 = alh[16 + c], a2 = alh[32 + c], a3 = alh[48 + c];
    float r0 = arh[c], r1 = arh[16 + c], r2 = arh[32 + c], r3 = arh[48 + c];
#pragma unroll
    for (int i = 0; i < 4; ++i)
#pragma unroll
        for (int r = 0; r < 4; ++r) {
            float pel = acc[i][0][r] * a0 + acc[i][1][r] * a1 + acc[i][2][r] * a2 + acc[i][3][r] * a3;
            float per = acc[i][0][r] * r0 + acc[i][1][r] * r1 + acc[i][2][r] * r2 + acc[i][3][r] * r3;
#pragma unroll
            for (int off = 8; off >= 1; off >>= 1) {
                pel += __shfl_xor(pel, off);
                per += __shfl_xor(per, off);
            }
            if (c == 0) {
                int grow = row0 + wm + i * 16 + q * 4 + r;
                if (grow < M) {
                    el[(size_t)grow * 4 + head] = pel;
                    er[(size_t)grow * 4 + head] = per;
                }
            }
        }
}

// ---------------- output MFMA GEMM: feat_o[N,40] bf16 = h_bf[N,256] @ W_o ----------------
// + fused output attention scores elo/ero[N] (replaces scores_out pass).
#define LDSK 40
#define BSTRIDE 264
__global__ __launch_bounds__(256) void gemm_out_mfma(const unsigned short* __restrict__ h,
                                                     const unsigned short* __restrict__ Wt,
                                                     const float* __restrict__ alo,
                                                     const float* __restrict__ aro,
                                                     unsigned short* __restrict__ feat_o,
                                                     float* __restrict__ elo,
                                                     float* __restrict__ ero, int N) {
    __shared__ unsigned short As[128 * LDSK];
    __shared__ unsigned short Bs[48 * BSTRIDE];
    const int tid = threadIdx.x;
    const int row0 = blockIdx.x * 128;
    const int lane = tid & 63, wid = tid >> 6;

#pragma unroll
    for (int i = 0; i < 6; ++i) {
        int f = tid + 256 * i;
        int n = f >> 5, kk = (f & 31) * 8;
        *(bf16x8*)&Bs[n * BSTRIDE + kk] = *(const bf16x8*)(Wt + n * 256 + kk);
    }
    __syncthreads();

    floatx4 acc[2][3] = {};
    for (int kb = 0; kb < 256; kb += 32) {
#pragma unroll
        for (int i = 0; i < 2; ++i) {
            int idx = tid + 256 * i;
            int r = idx >> 2, k8 = (idx & 3) * 8;
            int gr = row0 + r;
            bf16x8 v = {};
            if (gr < N) v = *(const bf16x8*)(h + (size_t)gr * 256 + kb + k8);
            *(bf16x8*)&As[r * LDSK + k8] = v;
        }
        __syncthreads();
        const int q = lane >> 4, m = lane & 15;
        bf16x8 af[2], bfr[3];
#pragma unroll
        for (int i = 0; i < 2; ++i)
            af[i] = *(const bf16x8*)&As[(wid * 32 + i * 16 + m) * LDSK + q * 8];
#pragma unroll
        for (int j = 0; j < 3; ++j)
            bfr[j] = *(const bf16x8*)&Bs[(j * 16 + m) * BSTRIDE + kb + q * 8];
#pragma unroll
        for (int i = 0; i < 2; ++i)
#pragma unroll
            for (int j = 0; j < 3; ++j)
                acc[i][j] = __builtin_amdgcn_mfma_f32_16x16x32_bf16(af[i], bfr[j], acc[i][j], 0, 0, 0);
        __syncthreads();
    }

    const int q = lane >> 4, c = lane & 15;
#pragma unroll
    for (int i = 0; i < 2; ++i)
#pragma unroll
        for (int j = 0; j < 3; ++j)
#pragma unroll
            for (int r = 0; r < 4; ++r) {
                int grow = row0 + wid * 32 + i * 16 + q * 4 + r;
                int gcol = j * 16 + c;
                if (grow < N && gcol < 40) feat_o[(size_t)grow * 40 + gcol] = f2bf(acc[i][j][r]);
            }

    // fused output scores: dot over 40 cols from fp32 accumulators
    float aj[3], rj[3];
#pragma unroll
    for (int j = 0; j < 3; ++j) {
        int gcol = j * 16 + c;
        aj[j] = gcol < 40 ? alo[gcol] : 0.f;
        rj[j] = gcol < 40 ? aro[gcol] : 0.f;
    }
#pragma unroll
    for (int i = 0; i < 2; ++i)
#pragma unroll
        for (int r = 0; r < 4; ++r) {
            float pl = acc[i][0][r] * aj[0] + acc[i][1][r] * aj[1] + acc[i][2][r] * aj[2];
            float pr = acc[i][0][r] * rj[0] + acc[i][1][r] * rj[1] + acc[i][2][r] * rj[2];
#pragma unroll
            for (int off = 8; off >= 1; off >>= 1) {
                pl += __shfl_xor(pl, off);
                pr += __shfl_xor(pr, off);
            }
            if (c == 0) {
                int grow = row0 + wid * 32 + i * 16 + q * 4 + r;
                if (grow < N) {
                    elo[grow] = pl;
                    ero[grow] = pr;
                }
            }
        }
}

// ---------------- hidden-layer aggregation: single pass + fused epilogue ----------------
__global__ __launch_bounds__(256) void aggregate_hidden(
    const unsigned short* __restrict__ feat, const float* __restrict__ el,
    const float* __restrict__ er, const int* __restrict__ start, const int* __restrict__ endp,
    const int* __restrict__ col, const float* __restrict__ bias, const float* __restrict__ lng,
    const float* __restrict__ lnb, const unsigned short* __restrict__ h_in,
    unsigned short* __restrict__ h_out, int N) {
    int node = blockIdx.x * 4 + (threadIdx.x >> 6);
    int lane = threadIdx.x & 63;
    if (node >= N) return;
    int begin = __builtin_amdgcn_readfirstlane(start[node]);
    int end = __builtin_amdgcn_readfirstlane(endp[node]);
    const int head = lane >> 4;
    const float erh = er[(size_t)node * 4 + head];

    const int ch = lane * 4;
    const unsigned short* fbase = feat + ch;
    const size_t hstr = 256;
    float4 acc = {0.f, 0.f, 0.f, 0.f};
    float ssum = 0.f;
    int e = begin;
    for (; e + 7 < end; e += 8) {
        int sA = col[e], sB = col[e + 1], sC = col[e + 2], sD = col[e + 3];
        int sE = col[e + 4], sF = col[e + 5], sG = col[e + 6], sH = col[e + 7];
        float eA = el[(size_t)sA * 4 + head];
        float eB = el[(size_t)sB * 4 + head];
        float eC = el[(size_t)sC * 4 + head];
        float eD = el[(size_t)sD * 4 + head];
        float eE = el[(size_t)sE * 4 + head];
        float eF = el[(size_t)sF * 4 + head];
        float eG = el[(size_t)sG * 4 + head];
        float eH = el[(size_t)sH * 4 + head];
        ushort4 uA = *(const ushort4*)(fbase + sA * hstr);
        ushort4 uB = *(const ushort4*)(fbase + sB * hstr);
        ushort4 uC = *(const ushort4*)(fbase + sC * hstr);
        ushort4 uD = *(const ushort4*)(fbase + sD * hstr);
        ushort4 uE = *(const ushort4*)(fbase + sE * hstr);
        ushort4 uF = *(const ushort4*)(fbase + sF * hstr);
        ushort4 uG = *(const ushort4*)(fbase + sG * hstr);
        ushort4 uH = *(const ushort4*)(fbase + sH * hstr);
        float wA = __expf(leaky(eA + erh));
        float wB = __expf(leaky(eB + erh));
        float wC = __expf(leaky(eC + erh));
        float wD = __expf(leaky(eD + erh));
        float wE = __expf(leaky(eE + erh));
        float wF = __expf(leaky(eF + erh));
        float wG = __expf(leaky(eG + erh));
        float wH = __expf(leaky(eH + erh));
        ssum += wA + wB + wC + wD + wE + wF + wG + wH;
        acc.x = fmaf(wA, bf2f(uA.x), acc.x); acc.y = fmaf(wA, bf2f(uA.y), acc.y);
        acc.z = fmaf(wA, bf2f(uA.z), acc.z); acc.w = fmaf(wA, bf2f(uA.w), acc.w);
        acc.x = fmaf(wB, bf2f(uB.x), acc.x); acc.y = fmaf(wB, bf2f(uB.y), acc.y);
        acc.z = fmaf(wB, bf2f(uB.z), acc.z); acc.w = fmaf(wB, bf2f(uB.w), acc.w);
        acc.x = fmaf(wC, bf2f(uC.x), acc.x); acc.y = fmaf(wC, bf2f(uC.y), acc.y);
        acc.z = fmaf(wC, bf2f(uC.z), acc.z); acc.w = fmaf(wC, bf2f(uC.w), acc.w);
        acc.x = fmaf(wD, bf2f(uD.x), acc.x); acc.y = fmaf(wD, bf2f(uD.y), acc.y);
        acc.z = fmaf(wD, bf2f(uD.z), acc.z); acc.w = fmaf(wD, bf2f(uD.w), acc.w);
        acc.x = fmaf(wE, bf2f(uE.x), acc.x); acc.y = fmaf(wE, bf2f(uE.y), acc.y);
        acc.z = fmaf(wE, bf2f(uE.z), acc.z); acc.w = fmaf(wE, bf2f(uE.w), acc.w);
        acc.x = fmaf(wF, bf2f(uF.x), acc.x); acc.y = fmaf(wF, bf2f(uF.y), acc.y);
        acc.z = fmaf(wF, bf2f(uF.z), acc.z); acc.w = fmaf(wF, bf2f(uF.w), acc.w);
        acc.x = fmaf(wG, bf2f(uG.x), acc.x); acc.y = fmaf(wG, bf2f(uG.y), acc.y);
        acc.z = fmaf(wG, bf2f(uG.z), acc.z); acc.w = fmaf(wG, bf2f(uG.w), acc.w);
        acc.x = fmaf(wH, bf2f(uH.x), acc.x); acc.y = fmaf(wH, bf2f(uH.y), acc.y);
        acc.z = fmaf(wH, bf2f(uH.z), acc.z); acc.w = fmaf(wH, bf2f(uH.w), acc.w);
    }
    for (; e < end; ++e) {
        int sA = col[e];
        float wA = __expf(leaky(el[(size_t)sA * 4 + head] + erh));
        ushort4 uA = *(const ushort4*)(fbase + sA * hstr);
        ssum += wA;
        acc.x = fmaf(wA, bf2f(uA.x), acc.x); acc.y = fmaf(wA, bf2f(uA.y), acc.y);
        acc.z = fmaf(wA, bf2f(uA.z), acc.z); acc.w = fmaf(wA, bf2f(uA.w), acc.w);
    }
    float inv = ssum > 0.f ? 1.f / ssum : 0.f;
    acc.x *= inv; acc.y *= inv; acc.z *= inv; acc.w *= inv;

    float4 bb = *(const float4*)(bias + ch);
    float x0 = acc.x + bb.x, x1 = acc.y + bb.y, x2 = acc.z + bb.z, x3 = acc.w + bb.w;
    x0 = x0 > 0.f ? x0 : expm1f(x0);
    x1 = x1 > 0.f ? x1 : expm1f(x1);
    x2 = x2 > 0.f ? x2 : expm1f(x2);
    x3 = x3 > 0.f ? x3 : expm1f(x3);
    float lsum = x0 + x1 + x2 + x3;
    float lsq = x0 * x0 + x1 * x1 + x2 * x2 + x3 * x3;
#pragma unroll
    for (int off = 32; off >= 1; off >>= 1) {
        lsum += __shfl_xor(lsum, off);
        lsq += __shfl_xor(lsq, off);
    }
    float mu = lsum * (1.f / 256.f);
    float var = lsq * (1.f / 256.f) - mu * mu;
    float rstd = rsqrtf(var + 1e-5f);
    float4 g4 = *(const float4*)(lng + ch);
    float4 b4 = *(const float4*)(lnb + ch);
    ushort4 hi = *(const ushort4*)(h_in + (size_t)node * 256 + ch);
    float y0 = (x0 - mu) * rstd * g4.x + b4.x;
    float y1 = (x1 - mu) * rstd * g4.y + b4.y;
    float y2 = (x2 - mu) * rstd * g4.z + b4.z;
    float y3 = (x3 - mu) * rstd * g4.w + b4.w;
    y0 = (y0 >= 0.f ? y0 : 0.2f * y0) + bf2f(hi.x);
    y1 = (y1 >= 0.f ? y1 : 0.2f * y1) + bf2f(hi.y);
    y2 = (y2 >= 0.f ? y2 : 0.2f * y2) + bf2f(hi.z);
    y3 = (y3 >= 0.f ? y3 : 0.2f * y3) + bf2f(hi.w);
    ushort4 o;
    o.x = f2bf(y0); o.y = f2bf(y1); o.z = f2bf(y2); o.w = f2bf(y3);
    *(ushort4*)(h_out + (size_t)node * 256 + ch) = o;
}

// ---------------- output aggregation: logits[N,40], single pass ----------------
__global__ __launch_bounds__(256) void aggregate_out(const unsigned short* __restrict__ feat_o,
                                                     const float* __restrict__ elo,
                                                     const float* __restrict__ ero,
                                                     const int* __restrict__ start,
                                                     const int* __restrict__ endp,
                                                     const int* __restrict__ col,
                                                     const float* __restrict__ bias_o,
                                                     float* __restrict__ out, int N) {
    int node = blockIdx.x * 4 + (threadIdx.x >> 6);
    int lane = threadIdx.x & 63;
    if (node >= N) return;
    int begin = __builtin_amdgcn_readfirstlane(start[node]);
    int end = __builtin_amdgcn_readfirstlane(endp[node]);
    float ern = ero[node];
    int cc = lane < 40 ? lane : 0;
    float acc = 0.f, ssum = 0.f;
    int e = begin;
    for (; e + 7 < end; e += 8) {
        int sA = col[e], sB = col[e + 1], sC = col[e + 2], sD = col[e + 3];
        int sE = col[e + 4], sF = col[e + 5], sG = col[e + 6], sH = col[e + 7];
        float eA = elo[sA], eB = elo[sB], eC = elo[sC], eD = elo[sD];
        float eE = elo[sE], eF = elo[sF], eG = elo[sG], eH = elo[sH];
        unsigned short fA = feat_o[(size_t)sA * 40 + cc];
        unsigned short fB = feat_o[(size_t)sB * 40 + cc];
        unsigned short fC = feat_o[(size_t)sC * 40 + cc];
        unsigned short fD = feat_o[(size_t)sD * 40 + cc];
        unsigned short fE = feat_o[(size_t)sE * 40 + cc];
        unsigned short fF = feat_o[(size_t)sF * 40 + cc];
        unsigned short fG = feat_o[(size_t)sG * 40 + cc];
        unsigned short fH = feat_o[(size_t)sH * 40 + cc];
        float wA = __expf(leaky(eA + ern));
        float wB = __expf(leaky(eB + ern));
        float wC = __expf(leaky(eC + ern));
        float wD = __expf(leaky(eD + ern));
        float wE = __expf(leaky(eE + ern));
        float wF = __expf(leaky(eF + ern));
        float wG = __expf(leaky(eG + ern));
        float wH = __expf(leaky(eH + ern));
        ssum += wA + wB + wC + wD + wE + wF + wG + wH;
        acc = fmaf(wA, bf2f(fA), acc);
        acc = fmaf(wB, bf2f(fB), acc);
        acc = fmaf(wC, bf2f(fC), acc);
        acc = fmaf(wD, bf2f(fD), acc);
        acc = fmaf(wE, bf2f(fE), acc);
        acc = fmaf(wF, bf2f(fF), acc);
        acc = fmaf(wG, bf2f(fG), acc);
        acc = fmaf(wH, bf2f(fH), acc);
    }
    for (; e < end; ++e) {
        int sA = col[e];
        float wA = __expf(leaky(elo[sA] + ern));
        ssum += wA;
        acc = fmaf(wA, bf2f(feat_o[(size_t)sA * 40 + cc]), acc);
    }
    float inv = ssum > 0.f ? 1.f / ssum : 0.f;
    if (lane < 40) out[(size_t)node * 40 + lane] = acc * inv + bias_o[lane];
}

// ---------------- launcher ----------------
extern "C" void kernel_launch(void* const* d_in, const int* in_sizes, int n_in,
                              void* d_out, int out_size, void* d_ws, size_t ws_size,
                              hipStream_t stream) {
    const float* x = (const float*)d_in[0];
    const float* W_h = (const float*)d_in[1];
    const float* al_h = (const float*)d_in[2];
    const float* ar_h = (const float*)d_in[3];
    const float* bias_h = (const float*)d_in[4];
    const float* ln_g = (const float*)d_in[5];
    const float* ln_b = (const float*)d_in[6];
    const float* W_o = (const float*)d_in[7];
    const float* al_o = (const float*)d_in[8];
    const float* ar_o = (const float*)d_in[9];
    const float* bias_o = (const float*)d_in[10];
    const int* esrc = (const int*)d_in[11];
    const int* edst = (const int*)d_in[12];
    const int N = in_sizes[0] / 256;
    const int E = in_sizes[11];
    float* out = (float*)d_out;

    char* ws = (char*)d_ws;
    size_t off = 0;
    auto walloc = [&](size_t bytes) -> void* {
        void* p = ws + off;
        off += (bytes + 255) & ~(size_t)255;
        return p;
    };
    unsigned short* x_bf = (unsigned short*)walloc((size_t)N * 256 * 2);
    unsigned short* h_bf = (unsigned short*)walloc((size_t)N * 256 * 2);
    unsigned short* feat_bf = (unsigned short*)walloc((size_t)N * 256 * 2);
    unsigned short* Wt = (unsigned short*)walloc((size_t)3 * 65536 * 2);
    unsigned short* Wt_o = (unsigned short*)walloc((size_t)48 * 256 * 2);
    float* el = (float*)walloc((size_t)N * 4 * 4);
    float* er = (float*)walloc((size_t)N * 4 * 4);
    int* counts = (int*)walloc(((size_t)N + 1) * 4);
    int* start = (int*)walloc((size_t)N * 4);
    int* endp = (int*)walloc((size_t)N * 4);
    int* col = (int*)walloc((size_t)E * 4);
    if (off > ws_size) return;

    const int TB = 256;
    convert_bf<<<(N * 64 + TB - 1) / TB, TB, 0, stream>>>(x, x_bf, N * 64);
    transpose_w<<<3 * 65536 / TB, TB, 0, stream>>>(W_h, Wt);
    transpose_wo<<<48, TB, 0, stream>>>(W_o, Wt_o);
    zero_i32<<<(N + 1 + TB - 1) / TB, TB, 0, stream>>>(counts, N + 1);
    hist_kernel<<<(E + TB - 1) / TB, TB, 0, stream>>>(edst, counts, E);
    alloc_kernel<<<(N + TB - 1) / TB, TB, 0, stream>>>(counts, start, endp, counts + N, N);
    scatter_kernel<<<(E + TB - 1) / TB, TB, 0, stream>>>(esrc, edst, endp, col, E);

    const int nb4 = (N + 3) / 4;
    const int gemm_grid = (N + 127) / 128;
    for (int l = 0; l < 3; ++l) {
        const unsigned short* hin = (l == 0) ? x_bf : h_bf;
        gemm_bf16_fused<<<gemm_grid, 512, 0, stream>>>(hin, Wt + (size_t)l * 65536,
                                                       al_h + l * 256, ar_h + l * 256,
                                                       feat_bf, el, er, N);
        aggregate_hidden<<<nb4, 256, 0, stream>>>(feat_bf, el, er, start, endp, col,
                                                  bias_h + l * 256, ln_g + l * 256,
                                                  ln_b + l * 256, hin, h_bf, N);
    }
    unsigned short* feat_o = feat_bf;
    float* elo = el;
    float* ero = er;
    gemm_out_mfma<<<(N + 127) / 128, 256, 0, stream>>>(h_bf, Wt_o, al_o, ar_o, feat_o, elo, ero, N);
    aggregate_out<<<nb4, 256, 0, stream>>>(feat_o, elo, ero, start, endp, col, bias_o, out, N);
}